// Round 5
// baseline (895.427 us; speedup 1.0000x reference)
//
#include <hip/hip_runtime.h>

#define BB 128
#define TT 1024
#define HH 512
#define KK 50

__device__ __forceinline__ float rl_f(float x, int lane) {
    return __int_as_float(__builtin_amdgcn_readlane(__float_as_int(x), lane));
}

// Opaque register barrier: forces A[B..B+9] into VGPRs at this point.
#define PIN10(A,B) asm volatile("" : "+v"(A[B+0]),"+v"(A[B+1]),"+v"(A[B+2]), \
    "+v"(A[B+3]),"+v"(A[B+4]),"+v"(A[B+5]),"+v"(A[B+6]),"+v"(A[B+7]), \
    "+v"(A[B+8]),"+v"(A[B+9]))
#define PIN50(A) do { PIN10(A,0); PIN10(A,10); PIN10(A,20); PIN10(A,30); PIN10(A,40); } while (0)

// ---------------------------------------------------------------------------
// Kernel 1: feats[bt][k] = sum_h hidden[bt][h] * W[k][h] + b[k]   (unchanged)
// ---------------------------------------------------------------------------
__global__ __launch_bounds__(256, 4) void gemm_feats(
    const float* __restrict__ hidden, const float* __restrict__ W,
    const float* __restrict__ bias, float* __restrict__ feats)
{
    __shared__ float At[32][132];
    __shared__ float Wt[32][68];
    const int tid = threadIdx.x;
    const int ri  = tid & 31;
    const int ki  = tid >> 5;
    const long row0 = (long)blockIdx.x * 128;

    float acc[4][8];
    #pragma unroll
    for (int r = 0; r < 4; ++r)
        #pragma unroll
        for (int k = 0; k < 8; ++k) acc[r][k] = 0.f;

    for (int h0 = 0; h0 < HH; h0 += 32) {
        #pragma unroll
        for (int it = 0; it < 4; ++it) {
            int idx = tid + 256 * it;
            int r = idx >> 3, hq = idx & 7;
            float4 a = *(const float4*)(hidden + (row0 + r) * HH + h0 + hq * 4);
            At[hq*4+0][r] = a.x; At[hq*4+1][r] = a.y;
            At[hq*4+2][r] = a.z; At[hq*4+3][r] = a.w;
        }
        #pragma unroll
        for (int it = 0; it < 2; ++it) {
            int idx = tid + 256 * it;
            int k = idx >> 3, hq = idx & 7;
            float4 w = make_float4(0.f, 0.f, 0.f, 0.f);
            if (k < KK) w = *(const float4*)(W + k * HH + h0 + hq * 4);
            Wt[hq*4+0][k] = w.x; Wt[hq*4+1][k] = w.y;
            Wt[hq*4+2][k] = w.z; Wt[hq*4+3][k] = w.w;
        }
        __syncthreads();
        #pragma unroll
        for (int h = 0; h < 32; ++h) {
            float a[4], w[8];
            *(float4*)a     = *(const float4*)&At[h][ri * 4];
            *(float4*)w     = *(const float4*)&Wt[h][ki * 8];
            *(float4*)(w+4) = *(const float4*)&Wt[h][ki * 8 + 4];
            #pragma unroll
            for (int r = 0; r < 4; ++r)
                #pragma unroll
                for (int k = 0; k < 8; ++k)
                    acc[r][k] += a[r] * w[k];
        }
        __syncthreads();
    }
    #pragma unroll
    for (int r = 0; r < 4; ++r) {
        long row = row0 + ri * 4 + r;
        #pragma unroll
        for (int k = 0; k < 8; ++k) {
            int kg = ki * 8 + k;
            if (kg < KK) feats[row * KK + kg] = acc[r][k] + bias[kg];
        }
    }
}

// ---------------------------------------------------------------------------
// Kernel 2: bp-free Viterbi forward. tc loaded VOLATILE (reload would be an
// illegal extra volatile read) + PIN50 + waves_per_eu(1,1) so the backend
// budgets 512 VGPRs and has no occupancy incentive to spill.
// ---------------------------------------------------------------------------
__global__ __attribute__((amdgpu_waves_per_eu(1, 1))) __launch_bounds__(64)
void viterbi_fwd(
    float* __restrict__ fv, const float* __restrict__ trans,
    const float* __restrict__ startT, const float* __restrict__ stopT,
    float* __restrict__ out_score, int* __restrict__ lastTag)
{
    const int b  = blockIdx.x;
    const int j  = threadIdx.x;
    const int jc = j < KK ? j : KK - 1;

    const volatile float* tv = trans;   // forbid re-loading inside the loop
    float tc[KK];
    #pragma unroll
    for (int i = 0; i < KK; ++i) tc[i] = tv[i * KK + jc];
    PIN50(tc);

    float* p = fv + (size_t)b * TT * KK;
    float v  = p[jc] + startT[jc];
    p[jc] = v;
    float f1 = p[KK + jc];
    float f2 = p[2 * KK + jc];
    float f3 = p[3 * KK + jc];

    #pragma unroll 1
    for (int t = 1; t < TT; ++t) {
        float f = f1; f1 = f2; f2 = f3;
        if (t + 3 < TT) f3 = p[(size_t)(t + 3) * KK + jc];

        float x[KK];
        #pragma unroll
        for (int i = 0; i < KK; ++i) x[i] = rl_f(v, i) + tc[i];

        float y[17];
        #pragma unroll
        for (int i = 0; i < 16; ++i)
            y[i] = fmaxf(fmaxf(x[3*i], x[3*i+1]), x[3*i+2]);
        y[16] = fmaxf(x[48], x[49]);
        float z[6];
        #pragma unroll
        for (int i = 0; i < 5; ++i)
            z[i] = fmaxf(fmaxf(y[3*i], y[3*i+1]), y[3*i+2]);
        z[5] = fmaxf(y[15], y[16]);
        float m = fmaxf(fmaxf(fmaxf(z[0], z[1]), z[2]),
                        fmaxf(fmaxf(z[3], z[4]), z[5]));

        v = f + m;
        p[(size_t)t * KK + jc] = v;
    }

    v += stopT[jc];
    float bestv = rl_f(v, 0); int besti = 0;
    #pragma unroll
    for (int i = 1; i < KK; ++i) {
        float xx = rl_f(v, i);
        if (xx > bestv) { bestv = xx; besti = i; }
    }
    if (j == 0) { out_score[b] = bestv; lastTag[b] = besti; }
}

// ---------------------------------------------------------------------------
// Kernel 3a: recompute backpointers per 32-step chunk + chunk maps. (unchanged)
// ---------------------------------------------------------------------------
__global__ __launch_bounds__(64, 4) void bt_maps(
    const float* __restrict__ v, const float* __restrict__ trans,
    unsigned char* __restrict__ bp, int* __restrict__ M)
{
    const int b = blockIdx.x, c = blockIdx.y;
    const int j = threadIdx.x;
    const int jc = j < KK ? j : KK - 1;

    float tc[KK];
    #pragma unroll
    for (int i = 0; i < KK; ++i) tc[i] = trans[i * KK + jc];
    PIN50(tc);

    const float* vb = v + (size_t)b * TT * KK;
    const int lo = c * 32;
    const int hi = min(c * 32 + 31, TT - 2);

    int cur = jc;
    float vnext = vb[(size_t)hi * KK + jc];

    #pragma unroll 1
    for (int s = hi; s >= lo; --s) {
        float vl = vnext;
        if (s > lo) vnext = vb[(size_t)(s - 1) * KK + jc];

        float best = rl_f(vl, 0) + tc[0];
        int   bi   = 0;
        #pragma unroll
        for (int i = 1; i < KK; ++i) {
            float cand = rl_f(vl, i) + tc[i];
            bool g = cand > best;            // strict: first index wins ties
            best = g ? cand : best;
            bi   = g ? i : bi;
        }

        if (j < KK)
            bp[((size_t)s * BB + b) * KK + j] = (unsigned char)bi;

        cur = __shfl(bi, cur, 64);           // compose: cur = bp_s[cur]
    }

    if (j < KK) M[(b * 32 + c) * KK + j] = cur;
}

// ---------------------------------------------------------------------------
// Kernel 3b: compose boundary tags serially, then 32 lanes re-walk chunks.
// ---------------------------------------------------------------------------
__global__ void bt_emit(const unsigned char* __restrict__ bp,
                        const int* __restrict__ M,
                        const int* __restrict__ lastTag,
                        float* __restrict__ tags)
{
    __shared__ int Ml[32][KK];
    __shared__ int e[33];
    const int b = blockIdx.x, tid = threadIdx.x;

    for (int i = tid; i < 32 * KK; i += 64)
        Ml[i / KK][i % KK] = M[b * 32 * KK + i];
    __syncthreads();

    if (tid == 0) {
        int cur = lastTag[b];
        e[32] = cur;
        for (int c = 31; c >= 0; --c) { cur = Ml[c][cur]; e[c] = cur; }
    }
    __syncthreads();

    if (tid < 32) {
        const int c  = tid;
        const int lo = c * 32;
        const int hi = min(c * 32 + 31, TT - 2);
        int cur = e[c + 1];
        for (int k = hi; k >= lo; --k) {
            cur = bp[((size_t)k * BB + b) * KK + cur];
            tags[(size_t)b * TT + k] = (float)cur;
        }
    }
    if (tid == 32) tags[(size_t)b * TT + (TT - 1)] = (float)lastTag[b];
}

// ---------------------------------------------------------------------------
extern "C" void kernel_launch(void* const* d_in, const int* in_sizes, int n_in,
                              void* d_out, int out_size, void* d_ws, size_t ws_size,
                              hipStream_t stream)
{
    const float* hidden = (const float*)d_in[0];
    const float* W      = (const float*)d_in[1];
    const float* bias   = (const float*)d_in[2];
    const float* trans  = (const float*)d_in[3];
    const float* startT = (const float*)d_in[4];
    const float* stopT  = (const float*)d_in[5];

    float* out = (float*)d_out;           // [0:128] best_score, [128:] tags

    char* ws = (char*)d_ws;
    float*         fv    = (float*)ws;                               // feats -> v in place
    unsigned char* bp    = (unsigned char*)(ws + 26214400);
    int*           M     = (int*)(ws + 32761600);
    int*           lastT = (int*)(ws + 33580800);

    gemm_feats<<<dim3((BB * TT) / 128), 256, 0, stream>>>(hidden, W, bias, fv);
    viterbi_fwd<<<dim3(BB), 64, 0, stream>>>(fv, trans, startT, stopT, out, lastT);
    bt_maps<<<dim3(BB, 32), 64, 0, stream>>>(fv, trans, bp, M);
    bt_emit<<<dim3(BB), 64, 0, stream>>>(bp, M, lastT, out + BB);
}